// Round 6
// baseline (4317.054 us; speedup 1.0000x reference)
//
#include <hip/hip_runtime.h>

#define HDIM 2048
#define TSTEPS 1024
#define NBLK 256
#define NTHR 512
#define CPB 8      // columns per block

typedef unsigned long long ull;

__device__ __forceinline__ int snake_src(int t) {
    int y = t >> 5, p = t & 31;
    return (y & 1) ? (y * 32 + 31 - p) : t;
}
__device__ __forceinline__ float sigmoid_f(float v) {
    return __builtin_amdgcn_rcpf(1.f + __expf(-v));
}
__device__ __forceinline__ float tanh_f(float v) {
    return 1.f - 2.f * __builtin_amdgcn_rcpf(__expf(2.f * v) + 1.f);
}

// ---------------------------------------------------------------------------
// Persistent kernel. 256 blocks x 512 threads; block owns 8 columns.
// Thread (c = tid&7, rr = tid>>3): column col = blk*8+c, rows [32rr, 32rr+32).
// 96 recurrent-weight floats per thread stay register-resident.
//
// KEY ALIGNMENT: thread polls slots [4*tid, 4*tid+4); its needed h rows
// [32rr, 32rr+32) are polled by lanes (lane&56)|j, j=0..7 of the SAME wave.
// => no LDS h buffer, no staging barrier. The wave's divergent poll loop is
// the synchronizer; intra-8-lane-group __shfl broadcasts distribute h.
// Per step: poll -> shfl+96 FMA -> 9 xor-shfl reduce -> red[] -> ONE
// __syncthreads -> wave0 finalizes 8 cols + one 64B coalesced tagged publish.
// h_old for the z-gate is carried in wave0 registers (it published it).
//
// Slots: {tag,f32} 8B agent-scope atomics, double-buffered; 0xAA poison tag
// is negative => never matches t in [1,1024], no workspace init needed.
// ---------------------------------------------------------------------------
__global__ __launch_bounds__(NTHR, 2) void gru_all(
    const float* __restrict__ x,
    const float* __restrict__ We,  const float* __restrict__ be,
    const float* __restrict__ Wir, const float* __restrict__ bir,
    const float* __restrict__ Wiz, const float* __restrict__ biz,
    const float* __restrict__ Win, const float* __restrict__ bin_,
    const float* __restrict__ Whr, const float* __restrict__ Whz,
    const float* __restrict__ Whn, const float* __restrict__ bhn,
    float* __restrict__ out, ull* __restrict__ s0, ull* __restrict__ s1)
{
    const int tid  = threadIdx.x;
    const int blk  = blockIdx.x;
    const int lane = tid & 63;
    const int wv   = tid >> 6;            // 0..7
    const int c    = tid & 7;
    const int rr   = tid >> 3;            // 0..63
    const int col  = blk * CPB + c;
    const int row0 = rr * 32;

    __shared__ float xs_l[TSTEPS];
    __shared__ float redc[8][6][9];       // prologue constants
    __shared__ float red[2][8][3][9];     // per-step partials (double buffer)

    // ---- stage snake-ordered x ----
    for (int i = tid; i < TSTEPS; i += NTHR) xs_l[i] = x[snake_src(i)];

    // ---- recurrent weights into registers (one-time, stays resident) ----
    float wr[32], wz[32], wn[32];
#pragma unroll
    for (int k = 0; k < 32; ++k) {
        size_t off = (size_t)(row0 + k) * HDIM + col;
        wr[k] = Whr[off];
        wz[k] = Whz[off];
        wn[k] = Whn[off];
    }

    // ---- rank-1 input-path constants for this thread's column ----
    {
        float vr = 0, vz = 0, vn = 0, cr = 0, cz = 0, cn = 0;
#pragma unroll 8
        for (int k = 0; k < 32; ++k) {
            size_t off = (size_t)(row0 + k) * HDIM + col;
            float we = We[row0 + k], bb = be[row0 + k];
            float w0 = Wir[off], w1 = Wiz[off], w2 = Win[off];
            vr = fmaf(we, w0, vr);  cr = fmaf(bb, w0, cr);
            vz = fmaf(we, w1, vz);  cz = fmaf(bb, w1, cz);
            vn = fmaf(we, w2, vn);  cn = fmaf(bb, w2, cn);
        }
#pragma unroll
        for (int m = 8; m < 64; m <<= 1) {
            vr += __shfl_xor(vr, m, 64); vz += __shfl_xor(vz, m, 64);
            vn += __shfl_xor(vn, m, 64); cr += __shfl_xor(cr, m, 64);
            cz += __shfl_xor(cz, m, 64); cn += __shfl_xor(cn, m, 64);
        }
        if (lane < CPB) {
            redc[wv][0][lane] = vr; redc[wv][1][lane] = vz; redc[wv][2][lane] = vn;
            redc[wv][3][lane] = cr; redc[wv][4][lane] = cz; redc[wv][5][lane] = cn;
        }
    }
    __syncthreads();

    // ---- wave 0 lanes 0..7 own the finalize path ----
    float vrc = 0, vzc = 0, vnc = 0, crc = 0, czc = 0, cnc = 0, bhc = 0;
    float h_prev = 0.f;                   // h_t[col], carried in-register
    if (wv == 0 && lane < CPB) {
#pragma unroll
        for (int w = 0; w < 8; ++w) {
            vrc += redc[w][0][lane]; vzc += redc[w][1][lane]; vnc += redc[w][2][lane];
            crc += redc[w][3][lane]; czc += redc[w][4][lane]; cnc += redc[w][5][lane];
        }
        crc += bir[col]; czc += biz[col]; cnc += bin_[col];
        bhc = bhn[col];

        // ---- step 0: h_0 == 0, fully local; publish h_1 with tag 1 ----
        float x0 = xs_l[0];
        float ar = fmaf(x0, vrc, crc);
        float az = fmaf(x0, vzc, czc);
        float an = fmaf(x0, vnc, cnc);
        float rg = sigmoid_f(ar), zg = sigmoid_f(az);
        float ng = tanh_f(fmaf(rg, bhc, an));
        h_prev = (1.f - zg) * ng;
        ull pkt = (1ULL << 32) | (ull)__float_as_uint(h_prev);
        __hip_atomic_store(&s1[col], pkt, __ATOMIC_RELAXED, __HIP_MEMORY_SCOPE_AGENT);
    }

    const int sbase = tid * 4;            // this thread's 4 h slots
    const int gb    = lane & 56;          // 8-lane group base

    for (int t = 1; t < TSTEPS; ++t) {
        ull* sin  = (t & 1) ? s1 : s0;
        ull* sout = (t & 1) ? s0 : s1;

        // ---- poll tagged slots; divergent loop = wave-level sync ----
        ull v0, v1, v2, v3;
        for (;;) {
            v0 = __hip_atomic_load(&sin[sbase+0], __ATOMIC_RELAXED, __HIP_MEMORY_SCOPE_AGENT);
            v1 = __hip_atomic_load(&sin[sbase+1], __ATOMIC_RELAXED, __HIP_MEMORY_SCOPE_AGENT);
            v2 = __hip_atomic_load(&sin[sbase+2], __ATOMIC_RELAXED, __HIP_MEMORY_SCOPE_AGENT);
            v3 = __hip_atomic_load(&sin[sbase+3], __ATOMIC_RELAXED, __HIP_MEMORY_SCOPE_AGENT);
            if ((int)(v0 >> 32) == t && (int)(v1 >> 32) == t &&
                (int)(v2 >> 32) == t && (int)(v3 >> 32) == t) break;
            __builtin_amdgcn_s_sleep(1);   // ~64 cyc backoff
        }
        float h0 = __uint_as_float((unsigned)v0);
        float h1 = __uint_as_float((unsigned)v1);
        float h2 = __uint_as_float((unsigned)v2);
        float h3 = __uint_as_float((unsigned)v3);

        // ---- distribute h within the 8-lane group; 96 register FMAs ----
        float a0 = 0.f, a1 = 0.f, a2 = 0.f;
#pragma unroll
        for (int j = 0; j < 8; ++j) {
            int src = gb | j;
            float b0 = __shfl(h0, src, 64);
            float b1 = __shfl(h1, src, 64);
            float b2 = __shfl(h2, src, 64);
            float b3 = __shfl(h3, src, 64);
            a0 = fmaf(b0, wr[4*j+0], a0); a1 = fmaf(b0, wz[4*j+0], a1); a2 = fmaf(b0, wn[4*j+0], a2);
            a0 = fmaf(b1, wr[4*j+1], a0); a1 = fmaf(b1, wz[4*j+1], a1); a2 = fmaf(b1, wn[4*j+1], a2);
            a0 = fmaf(b2, wr[4*j+2], a0); a1 = fmaf(b2, wz[4*j+2], a1); a2 = fmaf(b2, wn[4*j+2], a2);
            a0 = fmaf(b3, wr[4*j+3], a0); a1 = fmaf(b3, wz[4*j+3], a1); a2 = fmaf(b3, wn[4*j+3], a2);
        }
        // ---- reduce across the 8 row-groups in the wave (bits 3,4,5) ----
#pragma unroll
        for (int m = 8; m < 64; m <<= 1) {
            a0 += __shfl_xor(a0, m, 64);
            a1 += __shfl_xor(a1, m, 64);
            a2 += __shfl_xor(a2, m, 64);
        }
        float (*rd)[3][9] = red[t & 1];
        if (lane < CPB) { rd[wv][0][lane] = a0; rd[wv][1][lane] = a1; rd[wv][2][lane] = a2; }
        __syncthreads();                   // the ONLY barrier per step

        // ---- wave 0: finalize 8 columns, ONE coalesced 64B tagged publish ----
        if (wv == 0 && lane < CPB) {
            float Sr = 0, Sz = 0, Sn = 0;
#pragma unroll
            for (int w = 0; w < 8; ++w) {
                Sr += rd[w][0][lane]; Sz += rd[w][1][lane]; Sn += rd[w][2][lane];
            }
            float xt = xs_l[t];
            float ar = fmaf(xt, vrc, crc) + Sr;
            float az = fmaf(xt, vzc, czc) + Sz;
            float an = fmaf(xt, vnc, cnc);
            float rg = sigmoid_f(ar), zg = sigmoid_f(az);
            float ng = tanh_f(an + rg * (Sn + bhc));
            float hnew = (1.f - zg) * ng + zg * h_prev;
            h_prev = hnew;
            if (t == TSTEPS - 1) {
                out[col] = hnew;
            } else {
                ull pkt = ((ull)(unsigned)(t + 1) << 32) | (ull)__float_as_uint(hnew);
                __hip_atomic_store(&sout[col], pkt, __ATOMIC_RELAXED, __HIP_MEMORY_SCOPE_AGENT);
            }
        }
        // no trailing barrier: red[] is double-buffered; writers of step t+1
        // use the other parity, and a writer can only return to THIS parity
        // after passing a barrier wave 0 reaches post-read.
    }
}

extern "C" void kernel_launch(void* const* d_in, const int* in_sizes, int n_in,
                              void* d_out, int out_size, void* d_ws, size_t ws_size,
                              hipStream_t stream) {
    const float* x    = (const float*)d_in[0];
    const float* We   = (const float*)d_in[1];
    const float* be   = (const float*)d_in[2];
    const float* Wir  = (const float*)d_in[3];
    const float* bir  = (const float*)d_in[4];
    const float* Wiz  = (const float*)d_in[5];
    const float* biz  = (const float*)d_in[6];
    const float* Win  = (const float*)d_in[7];
    const float* bin_ = (const float*)d_in[8];
    const float* Whr  = (const float*)d_in[9];
    const float* Whz  = (const float*)d_in[10];
    const float* Whn  = (const float*)d_in[11];
    const float* bhn  = (const float*)d_in[12];

    ull* s0 = (ull*)d_ws;          // 2048 slots/buffer, no init needed
    ull* s1 = s0 + HDIM;

    gru_all<<<NBLK, NTHR, 0, stream>>>(x, We, be, Wir, bir, Wiz, biz, Win, bin_,
                                       Whr, Whz, Whn, bhn,
                                       (float*)d_out, s0, s1);
}